// Round 11
// baseline (68.129 us; speedup 1.0000x reference)
//
#include <hip/hip_runtime.h>
#include <math.h>

// Problem: B=64, T=512, D=1024.
//   v[b,d]     = sum_e W[d,e] * x[b,T-1,e]
//   scores[b,t]= sum_d x[b,t,d] * v[b,d]          (t in 0..510)
//   alpha      = softmax_t(scores)
//   c[b,d]     = sum_t alpha[b,t] * x[b,t,d]
//   out[b]     = concat(c[b,:], x[b,T-1,:])       (64 x 2048 fp32)
//
// HISTORY:
//  R4  3-kernel flash (G16, online softmax)  49.3 us
//  R5-R9 fused finalize w/ __threadfence     ~200 us (L2 wb/inv per block -> dead end)
//  R10 flash G32                             52.0 us
//  All flash variants ~50us vs ~22us stream floor -> per-row serial chain
//  (butterfly+exp+rescale between row loads) is the suspect. This round:
//  independent-score pass + block softmax + independent accumulate pass
//  (rows re-read from L2/L3, which holds x during replays).

#define BB 64
#define TT 512
#define DD 1024
#define TH 511           // valid history rows: 0..510
#define GROUPS 16        // blocks per batch
#define RPW 8            // rows per wave (4 waves * 8 = 32 rows per block)

// workspace (floats):
//   v      : [BB][DD]          off 0
//   partC  : [BB][GROUPS][DD]  off 65536
//   partML : [BB][GROUPS][2]   off 1114112

// ---------------- kernel 1: v = x_last @ W^T -------------------------------
// 256 blocks x 4 waves; wave = 4 d-rows (W stationary, 64 VGPR) x 16 batches.
__global__ __launch_bounds__(256, 4) void k_v(const float* __restrict__ x,
                                              const float* __restrict__ W,
                                              float* __restrict__ v) {
    const int wave = threadIdx.x >> 6;
    const int lane = threadIdx.x & 63;
    const int wg   = blockIdx.x * 4 + wave;   // 0..1023
    const int d0   = (wg >> 2) * 4;           // 256 d-quads
    const int bg   = wg & 3;                  // 4 batch-groups of 16

    float4 w4[4][4];
#pragma unroll
    for (int k = 0; k < 4; ++k)
#pragma unroll
        for (int j = 0; j < 4; ++j)
            w4[k][j] = *(const float4*)(W + (size_t)(d0 + k) * DD + j * 256 + lane * 4);

    float res = 0.f;                          // lane l -> (b = bg*16+(l>>2), d = d0+(l&3))
#pragma unroll 4
    for (int i = 0; i < 16; ++i) {
        const int b = bg * 16 + i;
        const float* xl = x + ((size_t)b * TT + (TT - 1)) * DD;
        float4 x4[4];
#pragma unroll
        for (int j = 0; j < 4; ++j)
            x4[j] = *(const float4*)(xl + j * 256 + lane * 4);
#pragma unroll
        for (int k = 0; k < 4; ++k) {
            float p = 0.f;
#pragma unroll
            for (int j = 0; j < 4; ++j)
                p += w4[k][j].x * x4[j].x + w4[k][j].y * x4[j].y +
                     w4[k][j].z * x4[j].z + w4[k][j].w * x4[j].w;
#pragma unroll
            for (int m = 1; m < 64; m <<= 1) p += __shfl_xor(p, m, 64);
            if (lane == i * 4 + k) res = p;
        }
    }
    v[(size_t)(bg * 16 + (lane >> 2)) * DD + d0 + (lane & 3)] = res;
}

// ---------------- kernel 2: two-pass chunk (independent rows) --------------
// 1024 blocks (64 b x 16 groups), 256 thr.
// Phase A: 8 INDEPENDENT row-dots per wave (all loads in flight), scores->LDS.
// Phase B: block softmax over 32 scores (one barrier each side).
// Phase C: 8 INDEPENDENT weighted accumulates, rows re-read from L2/L3.
// Block-global max => cross-wave combine is a plain sum.
__global__ __launch_bounds__(256, 4) void k_chunk(const float* __restrict__ x,
                                                  const float* __restrict__ v,
                                                  float* __restrict__ partC,
                                                  float* __restrict__ partML) {
    __shared__ float cw[4][DD];               // 16 KB combine buffer
    __shared__ float sloc[32];
    __shared__ float eloc[32];
    __shared__ float msh;

    const int b     = blockIdx.x >> 4;
    const int g     = blockIdx.x & (GROUPS - 1);
    const int wave  = threadIdx.x >> 6;
    const int lane  = threadIdx.x & 63;
    const int col   = lane * 4;
    const int rbase = g * 32 + wave * RPW;    // <= 504

    const float* xb = x + (size_t)b * TT * DD;

    float4 v4[4];
#pragma unroll
    for (int j = 0; j < 4; ++j)
        v4[j] = *(const float4*)(v + (size_t)b * DD + j * 256 + col);

    // ---- phase A: independent scores ----
#pragma unroll
    for (int i = 0; i < RPW; ++i) {
        const int r  = rbase + i;
        const int rc = min(r, TH - 1);        // clamped addr; masked below
        const float* p = xb + (size_t)rc * DD + col;
        const float4 x0 = *(const float4*)(p);
        const float4 x1 = *(const float4*)(p + 256);
        const float4 x2 = *(const float4*)(p + 512);
        const float4 x3 = *(const float4*)(p + 768);
        float s = v4[0].x * x0.x + v4[0].y * x0.y + v4[0].z * x0.z + v4[0].w * x0.w
                + v4[1].x * x1.x + v4[1].y * x1.y + v4[1].z * x1.z + v4[1].w * x1.w
                + v4[2].x * x2.x + v4[2].y * x2.y + v4[2].z * x2.z + v4[2].w * x2.w
                + v4[3].x * x3.x + v4[3].y * x3.y + v4[3].z * x3.z + v4[3].w * x3.w;
#pragma unroll
        for (int mm = 1; mm < 64; mm <<= 1) s += __shfl_xor(s, mm, 64);
        if (r >= TH) s = -INFINITY;
        if (lane == 0) sloc[wave * RPW + i] = s;
    }
    __syncthreads();

    // ---- phase B: block softmax stats (threads 0..31) ----
    if (threadIdx.x < 32) {
        float M = -INFINITY;
#pragma unroll
        for (int t = 0; t < 32; ++t) M = fmaxf(M, sloc[t]);
        eloc[threadIdx.x] = __expf(sloc[threadIdx.x] - M);  // exp(-inf)=0 for invalid
        if (threadIdx.x == 0) msh = M;
    }
    __syncthreads();

    // ---- phase C: independent weighted accumulate (rows from L2/L3) ----
    float4 acc0 = make_float4(0,0,0,0), acc1 = make_float4(0,0,0,0);
    float4 acc2 = make_float4(0,0,0,0), acc3 = make_float4(0,0,0,0);
#pragma unroll
    for (int i = 0; i < RPW; ++i) {
        const int rc = min(rbase + i, TH - 1);
        const float  e = eloc[wave * RPW + i];      // 0 for invalid row
        const float* p = xb + (size_t)rc * DD + col;
        const float4 x0 = *(const float4*)(p);
        const float4 x1 = *(const float4*)(p + 256);
        const float4 x2 = *(const float4*)(p + 512);
        const float4 x3 = *(const float4*)(p + 768);
        acc0.x += e * x0.x; acc0.y += e * x0.y; acc0.z += e * x0.z; acc0.w += e * x0.w;
        acc1.x += e * x1.x; acc1.y += e * x1.y; acc1.z += e * x1.z; acc1.w += e * x1.w;
        acc2.x += e * x2.x; acc2.y += e * x2.y; acc2.z += e * x2.z; acc2.w += e * x2.w;
        acc3.x += e * x3.x; acc3.y += e * x3.y; acc3.z += e * x3.z; acc3.w += e * x3.w;
    }

    // ---- epilogue: plain sum across waves (shared max) ----
    *(float4*)(&cw[wave][0 * 256 + col]) = acc0;
    *(float4*)(&cw[wave][1 * 256 + col]) = acc1;
    *(float4*)(&cw[wave][2 * 256 + col]) = acc2;
    *(float4*)(&cw[wave][3 * 256 + col]) = acc3;
    __syncthreads();

    const int d0 = threadIdx.x * 4;
    const float4 s0 = *(const float4*)(&cw[0][d0]);
    const float4 s1 = *(const float4*)(&cw[1][d0]);
    const float4 s2 = *(const float4*)(&cw[2][d0]);
    const float4 s3 = *(const float4*)(&cw[3][d0]);
    float4 o;
    o.x = s0.x + s1.x + s2.x + s3.x;
    o.y = s0.y + s1.y + s2.y + s3.y;
    o.z = s0.z + s1.z + s2.z + s3.z;
    o.w = s0.w + s1.w + s2.w + s3.w;
    *(float4*)(partC + ((size_t)b * GROUPS + g) * DD + d0) = o;

    if (threadIdx.x == 0) {
        float L = 0.f;
#pragma unroll
        for (int t = 0; t < 32; ++t) L += eloc[t];
        partML[((size_t)b * GROUPS + g) * 2 + 0] = msh;
        partML[((size_t)b * GROUPS + g) * 2 + 1] = L;
    }
}

// ---------------- kernel 3: combine partials, divide, append x_last --------
__global__ __launch_bounds__(256) void k_final(const float* __restrict__ x,
                                               const float* __restrict__ partC,
                                               const float* __restrict__ partML,
                                               float* __restrict__ out) {
    const int b = blockIdx.x >> 2;
    const int q = blockIdx.x & 3;
    __shared__ float wgt[GROUPS];
    __shared__ float lsh;

    if (threadIdx.x < GROUPS) {
        float M = -INFINITY;
        for (int cc = 0; cc < GROUPS; ++cc)
            M = fmaxf(M, partML[((size_t)b * GROUPS + cc) * 2]);
        wgt[threadIdx.x] = __expf(partML[((size_t)b * GROUPS + threadIdx.x) * 2] - M);
    }
    __syncthreads();
    if (threadIdx.x == 0) {
        float L = 0.f;
        for (int cc = 0; cc < GROUPS; ++cc)
            L += partML[((size_t)b * GROUPS + cc) * 2 + 1] * wgt[cc];
        lsh = 1.f / L;
    }
    __syncthreads();
    const float invL = lsh;

    const int d = q * 256 + threadIdx.x;
    float acc = 0.f;
#pragma unroll
    for (int cc = 0; cc < GROUPS; ++cc)
        acc += wgt[cc] * partC[((size_t)b * GROUPS + cc) * DD + d];
    out[(size_t)b * 2048 + d] = acc * invL;
    out[(size_t)b * 2048 + 1024 + d] = x[((size_t)b * TT + (TT - 1)) * DD + d];
}

extern "C" void kernel_launch(void* const* d_in, const int* in_sizes, int n_in,
                              void* d_out, int out_size, void* d_ws, size_t ws_size,
                              hipStream_t stream) {
    const float* x = (const float*)d_in[0];   // (64,512,1024) fp32
    const float* W = (const float*)d_in[1];   // (1024,1024) fp32
    float* out = (float*)d_out;               // (64,2048) fp32

    float* ws     = (float*)d_ws;
    float* v      = ws;                                           // 65536
    float* partC  = ws + 65536;                                   // 1048576
    float* partML = ws + 65536 + (size_t)BB * GROUPS * DD;        // 2048

    k_v<<<256, 256, 0, stream>>>(x, W, v);
    k_chunk<<<BB * GROUPS, 256, 0, stream>>>(x, v, partC, partML);
    k_final<<<BB * 4, 256, 0, stream>>>(x, partC, partML, out);
}

// Round 12
// 41.262 us; speedup vs baseline: 1.6511x; 1.6511x over previous
//
#include <hip/hip_runtime.h>
#include <math.h>

// Problem: B=64, T=512, D=1024.
//   v[b,d]     = sum_e W[d,e] * x[b,T-1,e]
//   scores[b,t]= sum_d x[b,t,d] * v[b,d]          (t in 0..510)
//   alpha      = softmax_t(scores)
//   c[b,d]     = sum_t alpha[b,t] * x[b,t,d]
//   out[b]     = concat(c[b,:], x[b,T-1,:])       (64 x 2048 fp32)
//
// HISTORY:
//  R4  3-kernel flash (G16, online, prefetch)    49.3 us
//  R5-R9 fused finalize w/ __threadfence         ~200 us (L2 wb/inv -> dead end)
//  R10 flash G32 lb(256,4)                       52.0 us
//  R11 two-pass (x read twice)                   68.1 us  (+16us = 2nd pass BW
//      cost -> k_chunk single-read is ~25-30us, near floor; the other ~25us
//      lives in k_v (1 wave/SIMD, serial butterflies), k_final, launch gaps)
//  R12: k_v 4x parallelism; k_chunk minimal-reg TLP (no prefetch, lb(256,6)).

#define BB 64
#define TT 512
#define DD 1024
#define TH 511           // valid history rows: 0..510
#define GROUPS 32        // blocks per batch
#define RPW 4            // rows per wave (4 waves * 4 = 16 rows per block)

// workspace (floats):
//   v      : [BB][DD]          off 0            (65536)
//   partC  : [BB][GROUPS][DD]  off 65536        (2097152, 8 MB)
//   partML : [BB][GROUPS][2]   off 2162688      (4096)

// ---------------- kernel 1: v = x_last @ W^T -------------------------------
// 1024 blocks x 4 waves = 4096 wave-groups: (256 d-quads) x (16 batch-groups
// of 4). Wave: W rows stationary (64 VGPR), 4 batches, 16 butterflies.
// 4 blocks/CU, 4 waves/SIMD (vs 1 before) -> latency-bound chains overlap.
__global__ __launch_bounds__(256, 4) void k_v(const float* __restrict__ x,
                                              const float* __restrict__ W,
                                              float* __restrict__ v) {
    const int wave = threadIdx.x >> 6;
    const int lane = threadIdx.x & 63;
    const int wg   = blockIdx.x * 4 + wave;   // 0..4095
    const int d0   = (wg >> 4) * 4;           // 256 d-quads
    const int bg   = wg & 15;                 // 16 batch-groups of 4

    float4 w4[4][4];
#pragma unroll
    for (int k = 0; k < 4; ++k)
#pragma unroll
        for (int j = 0; j < 4; ++j)
            w4[k][j] = *(const float4*)(W + (size_t)(d0 + k) * DD + j * 256 + lane * 4);

    float res = 0.f;                          // lanes 0..15: (b=bg*4+(l>>2), d=d0+(l&3))
#pragma unroll
    for (int i = 0; i < 4; ++i) {
        const int b = bg * 4 + i;
        const float* xl = x + ((size_t)b * TT + (TT - 1)) * DD;
        float4 x4[4];
#pragma unroll
        for (int j = 0; j < 4; ++j)
            x4[j] = *(const float4*)(xl + j * 256 + lane * 4);
        float p[4];
#pragma unroll
        for (int k = 0; k < 4; ++k)
            p[k] = w4[k][0].x * x4[0].x + w4[k][0].y * x4[0].y + w4[k][0].z * x4[0].z + w4[k][0].w * x4[0].w
                 + w4[k][1].x * x4[1].x + w4[k][1].y * x4[1].y + w4[k][1].z * x4[1].z + w4[k][1].w * x4[1].w
                 + w4[k][2].x * x4[2].x + w4[k][2].y * x4[2].y + w4[k][2].z * x4[2].z + w4[k][2].w * x4[2].w
                 + w4[k][3].x * x4[3].x + w4[k][3].y * x4[3].y + w4[k][3].z * x4[3].z + w4[k][3].w * x4[3].w;
#pragma unroll
        for (int mm = 1; mm < 64; mm <<= 1) {
#pragma unroll
            for (int k = 0; k < 4; ++k) p[k] += __shfl_xor(p[k], mm, 64);
        }
#pragma unroll
        for (int k = 0; k < 4; ++k)
            if (lane == i * 4 + k) res = p[k];
    }
    if (lane < 16)
        v[(size_t)(bg * 4 + (lane >> 2)) * DD + d0 + (lane & 3)] = res;
}

// ---------------- kernel 2: minimal-register flash chunk (TLP-hiding) ------
// 2048 blocks (64 b x 32 groups), 256 thr. Wave: 4 rows, online softmax,
// NO prefetch buffers (row regs reused for accumulate) -> ~65 VGPR,
// lb(256,6) -> 6 waves/SIMD; TLP hides the per-row load+chain latency.
__global__ __launch_bounds__(256, 6) void k_chunk(const float* __restrict__ x,
                                                  const float* __restrict__ v,
                                                  float* __restrict__ partC,
                                                  float* __restrict__ partML) {
    __shared__ float cw[4][DD];               // 16 KB combine buffer
    __shared__ float cml[4][2];

    const int b    = blockIdx.x >> 5;         // / GROUPS
    const int g    = blockIdx.x & (GROUPS - 1);
    const int wave = threadIdx.x >> 6;
    const int lane = threadIdx.x & 63;
    const int r0   = g * 16 + wave * RPW;     // <= 508
    const int col  = lane * 4;

    const float* xb = x + (size_t)b * TT * DD;
    const float* vb = v + (size_t)b * DD + col;
    const float4 vv0 = *(const float4*)(vb);
    const float4 vv1 = *(const float4*)(vb + 256);
    const float4 vv2 = *(const float4*)(vb + 512);
    const float4 vv3 = *(const float4*)(vb + 768);

    float m = -INFINITY, l = 0.f;
    float4 acc0 = make_float4(0,0,0,0), acc1 = make_float4(0,0,0,0);
    float4 acc2 = make_float4(0,0,0,0), acc3 = make_float4(0,0,0,0);

#pragma unroll
    for (int i = 0; i < RPW; ++i) {
        const int r  = r0 + i;
        const int rc = min(r, TH - 1);        // clamped addr; masked via score
        const float* p = xb + (size_t)rc * DD + col;
        const float4 x0 = *(const float4*)(p);
        const float4 x1 = *(const float4*)(p + 256);
        const float4 x2 = *(const float4*)(p + 512);
        const float4 x3 = *(const float4*)(p + 768);

        float s = vv0.x * x0.x + vv0.y * x0.y + vv0.z * x0.z + vv0.w * x0.w
                + vv1.x * x1.x + vv1.y * x1.y + vv1.z * x1.z + vv1.w * x1.w
                + vv2.x * x2.x + vv2.y * x2.y + vv2.z * x2.z + vv2.w * x2.w
                + vv3.x * x3.x + vv3.y * x3.y + vv3.z * x3.z + vv3.w * x3.w;
#pragma unroll
        for (int mm = 1; mm < 64; mm <<= 1) s += __shfl_xor(s, mm, 64);
        if (r >= TH) s = -INFINITY;           // invalid tail row -> e = 0

        const float mnew = fmaxf(m, s);
        if (mnew > m) {                        // wave-uniform branch
            const float sc = __expf(m - mnew); // first iter: exp(-inf)=0
            acc0.x *= sc; acc0.y *= sc; acc0.z *= sc; acc0.w *= sc;
            acc1.x *= sc; acc1.y *= sc; acc1.z *= sc; acc1.w *= sc;
            acc2.x *= sc; acc2.y *= sc; acc2.z *= sc; acc2.w *= sc;
            acc3.x *= sc; acc3.y *= sc; acc3.z *= sc; acc3.w *= sc;
            l *= sc; m = mnew;
        }
        const float e = __expf(s - m);
        l += e;
        acc0.x += e * x0.x; acc0.y += e * x0.y; acc0.z += e * x0.z; acc0.w += e * x0.w;
        acc1.x += e * x1.x; acc1.y += e * x1.y; acc1.z += e * x1.z; acc1.w += e * x1.w;
        acc2.x += e * x2.x; acc2.y += e * x2.y; acc2.z += e * x2.z; acc2.w += e * x2.w;
        acc3.x += e * x3.x; acc3.y += e * x3.y; acc3.z += e * x3.z; acc3.w += e * x3.w;
    }

    // one cross-wave combine per block
    *(float4*)(&cw[wave][0 * 256 + col]) = acc0;
    *(float4*)(&cw[wave][1 * 256 + col]) = acc1;
    *(float4*)(&cw[wave][2 * 256 + col]) = acc2;
    *(float4*)(&cw[wave][3 * 256 + col]) = acc3;
    if (lane == 0) { cml[wave][0] = m; cml[wave][1] = l; }
    __syncthreads();

    const float M = fmaxf(fmaxf(cml[0][0], cml[1][0]), fmaxf(cml[2][0], cml[3][0]));
    const float w0 = __expf(cml[0][0] - M), w1 = __expf(cml[1][0] - M);
    const float w2 = __expf(cml[2][0] - M), w3 = __expf(cml[3][0] - M);
    const float L = w0 * cml[0][1] + w1 * cml[1][1] + w2 * cml[2][1] + w3 * cml[3][1];

    const int d0 = threadIdx.x * 4;
    const float4 s0 = *(const float4*)(&cw[0][d0]);
    const float4 s1 = *(const float4*)(&cw[1][d0]);
    const float4 s2 = *(const float4*)(&cw[2][d0]);
    const float4 s3 = *(const float4*)(&cw[3][d0]);
    float4 o;
    o.x = w0 * s0.x + w1 * s1.x + w2 * s2.x + w3 * s3.x;
    o.y = w0 * s0.y + w1 * s1.y + w2 * s2.y + w3 * s3.y;
    o.z = w0 * s0.z + w1 * s1.z + w2 * s2.z + w3 * s3.z;
    o.w = w0 * s0.w + w1 * s1.w + w2 * s2.w + w3 * s3.w;
    *(float4*)(partC + ((size_t)b * GROUPS + g) * DD + d0) = o;
    if (threadIdx.x == 0) {
        partML[((size_t)b * GROUPS + g) * 2 + 0] = M;
        partML[((size_t)b * GROUPS + g) * 2 + 1] = L;
    }
}

// ---------------- kernel 3: combine partials, divide, append x_last --------
__global__ __launch_bounds__(256) void k_final(const float* __restrict__ x,
                                               const float* __restrict__ partC,
                                               const float* __restrict__ partML,
                                               float* __restrict__ out) {
    const int b = blockIdx.x >> 2;
    const int q = blockIdx.x & 3;
    __shared__ float wgt[GROUPS];
    __shared__ float lsh;

    if (threadIdx.x < GROUPS) {
        float M = -INFINITY;
        for (int cc = 0; cc < GROUPS; ++cc)
            M = fmaxf(M, partML[((size_t)b * GROUPS + cc) * 2]);
        wgt[threadIdx.x] = __expf(partML[((size_t)b * GROUPS + threadIdx.x) * 2] - M);
    }
    __syncthreads();
    if (threadIdx.x == 0) {
        float L = 0.f;
        for (int cc = 0; cc < GROUPS; ++cc)
            L += partML[((size_t)b * GROUPS + cc) * 2 + 1] * wgt[cc];
        lsh = 1.f / L;
    }
    __syncthreads();
    const float invL = lsh;

    const int d = q * 256 + threadIdx.x;
    float acc = 0.f;
#pragma unroll 8
    for (int cc = 0; cc < GROUPS; ++cc)
        acc += wgt[cc] * partC[((size_t)b * GROUPS + cc) * DD + d];
    out[(size_t)b * 2048 + d] = acc * invL;
    out[(size_t)b * 2048 + 1024 + d] = x[((size_t)b * TT + (TT - 1)) * DD + d];
}

extern "C" void kernel_launch(void* const* d_in, const int* in_sizes, int n_in,
                              void* d_out, int out_size, void* d_ws, size_t ws_size,
                              hipStream_t stream) {
    const float* x = (const float*)d_in[0];   // (64,512,1024) fp32
    const float* W = (const float*)d_in[1];   // (1024,1024) fp32
    float* out = (float*)d_out;               // (64,2048) fp32

    float* ws     = (float*)d_ws;             // ~8.5 MB
    float* v      = ws;                                           // 65536
    float* partC  = ws + 65536;                                   // 2097152
    float* partML = ws + 65536 + (size_t)BB * GROUPS * DD;        // 4096

    k_v<<<1024, 256, 0, stream>>>(x, W, v);
    k_chunk<<<BB * GROUPS, 256, 0, stream>>>(x, v, partC, partML);
    k_final<<<BB * 4, 256, 0, stream>>>(x, partC, partML, out);
}